// Round 12
// baseline (336.405 us; speedup 1.0000x reference)
//
#include <hip/hip_runtime.h>

typedef unsigned short u16;
typedef __attribute__((ext_vector_type(8))) short short8;
typedef __attribute__((ext_vector_type(4))) unsigned short u16x4;
typedef __attribute__((ext_vector_type(8))) __bf16 bf16x8;
typedef __attribute__((ext_vector_type(4))) float f32x4;

#define B_SZ 4
#define NSEQ 8192
#define DMODEL 1024
#define MROWS 32768
#define QKVCOLS 3072

static __device__ __forceinline__ u16 f2bf(float f) {
  unsigned u = __builtin_bit_cast(unsigned, f);
  u += 0x7fffu + ((u >> 16) & 1u);
  return (u16)(u >> 16);
}
static __device__ __forceinline__ float bf2f(u16 h) {
  return __builtin_bit_cast(float, ((unsigned)h) << 16);
}
static __device__ __forceinline__ void gload16(const u16* g, u16* l) {
  __builtin_amdgcn_global_load_lds(
      (const __attribute__((address_space(1))) unsigned*)g,
      (__attribute__((address_space(3))) unsigned*)l, 16, 0, 0);
}

// ---------------- fp32 -> bf16 convert ----------------
__global__ __launch_bounds__(256) void k_convert(const float* __restrict__ in,
                                                 u16* __restrict__ out, long n) {
  long i = ((long)blockIdx.x * 256 + threadIdx.x) * 4;
  if (i >= n) return;
  f32x4 v = *(const f32x4*)(in + i);
  u16x4 o;
  o[0] = f2bf(v[0]); o[1] = f2bf(v[1]); o[2] = f2bf(v[2]); o[3] = f2bf(v[3]);
  *(u16x4*)(out + i) = o;
}

// ---------------- wvb[i][k] = bf16(w_qkv[i][2048+k])  (1024x1024) ----------------
__global__ __launch_bounds__(256) void k_cv(const float* __restrict__ wq,
                                            u16* __restrict__ wvb) {
  int idx = (blockIdx.x * 256 + threadIdx.x) * 4;
  int i = idx >> 10, k = idx & 1023;
  f32x4 v = *(const f32x4*)(wq + (long)i * QKVCOLS + 2048 + k);
  u16x4 o;
  o[0] = f2bf(v[0]); o[1] = f2bf(v[1]); o[2] = f2bf(v[2]); o[3] = f2bf(v[3]);
  *(u16x4*)(wvb + idx) = o;
}

// ---------------- transpose fp32[R][C] -> bf16[C][R] ----------------
__global__ __launch_bounds__(256) void k_transpose(const float* __restrict__ in,
                                                   u16* __restrict__ out, int R, int C) {
  __shared__ float tile[32][33];
  int c0 = blockIdx.x * 32, r0 = blockIdx.y * 32;
  int tx = threadIdx.x, ty = threadIdx.y;  // (32, 8)
#pragma unroll
  for (int j = 0; j < 32; j += 8)
    tile[ty + j][tx] = in[(long)(r0 + ty + j) * C + c0 + tx];
  __syncthreads();
#pragma unroll
  for (int j = 0; j < 32; j += 8)
    out[(long)(c0 + ty + j) * R + r0 + tx] = f2bf(tile[tx][ty + j]);
}

// ============ 256x256 4-phase (m201-style) bf16 GEMM: C = A[M][K] * B^T[N][K] ============
// EPI 0: qk fused epilogue -> qhat/khat head-major [bh][n][64] (+softmax / exp+colsum)
// EPI 1: fp32 + bias to Cf
#define MFMA_QUAD(Qm, Qn, A_, B_)                                              \
  _Pragma("unroll") for (int m = 0; m < 4; ++m)                                \
  _Pragma("unroll") for (int n = 0; n < 2; ++n)                                \
    acc[Qm][Qn][m][n] = __builtin_amdgcn_mfma_f32_16x16x32_bf16(A_[m][1], B_[n][1], \
        __builtin_amdgcn_mfma_f32_16x16x32_bf16(A_[m][0], B_[n][0], acc[Qm][Qn][m][n], 0, 0, 0), 0, 0, 0);

template <int EPI, int K, int LDA, int NBN, int LDC, long BSTR>
__global__ __launch_bounds__(512, 2) void k_gemm256(
    const u16* __restrict__ A, const u16* __restrict__ Bp,
    const float* __restrict__ bias, u16* __restrict__ qh,
    u16* __restrict__ kh, float* __restrict__ Cf, float* __restrict__ S) {
  __shared__ __align__(16) u16 sm[65536];  // A0|A1|B0|B1, 16384 u16 each
  const int t = threadIdx.x;
  const int lane = t & 63;
  const int w = t >> 6;       // 0..7
  const int wq = w >> 2;      // row-half within quadrant
  const int wn = w & 3;       // col group
  const int lr = lane & 15;
  const int hi = lane >> 4;
  const int l3 = lane >> 3;

  // XCD swizzle + bm-group-of-8
  const int nwg = gridDim.x;
  const int bid = blockIdx.x;
  const int swz = (bid & 7) * (nwg >> 3) + (bid >> 3);
  const int per = 8 * NBN;
  const int grp = swz / per, rem = swz % per;
  const int bm = grp * 8 + (rem & 7);
  const int bn = rem / 8;

  const u16* B = Bp + (long)(bm >> 5) * BSTR;
  const int gcol = ((lane & 7) ^ l3) * 8;  // swizzled k-offset (elements)

  auto stA = [&](int tile, int half, int buf) {
    u16* dst = &sm[buf * 16384 + (half * 128 + w * 16) * 64];
    const u16* g = A + ((long)(bm * 256 + half * 128 + w * 16 + l3)) * LDA + tile * 64 + gcol;
    gload16(g, dst);
    gload16(g + 8 * (long)LDA, dst + 8 * 64);
  };
  auto stB = [&](int tile, int half, int buf) {
#pragma unroll
    for (int L = 0; L < 2; ++L) {
      int base = half * 128 + w * 16 + L * 8;  // LDS B row base
      int grow = bn * 256 + ((base >> 5) & 3) * 64 + half * 32 + (base & 31) + l3;
      const u16* g = B + (long)grow * K + tile * 64 + gcol;
      gload16(g, &sm[32768 + buf * 16384 + base * 64]);
    }
  };

  const int su = (lr & 7) << 3;
  const int cu0 = (hi * 8) ^ su;         // kk=0 swizzled col (u16 units)
  const int cu1 = (32 + hi * 8) ^ su;    // kk=1
  const int arow = wq * 64 + lr;
  const int brow = wn * 32 + lr;

  auto ldA = [&](int buf, int Qm, int m, int kk) -> bf16x8 {
    return *(const bf16x8*)&sm[buf * 16384 + (Qm * 128 + arow + m * 16) * 64 + (kk ? cu1 : cu0)];
  };
  auto ldB = [&](int buf, int Qn, int n, int kk) -> bf16x8 {
    return *(const bf16x8*)&sm[32768 + buf * 16384 + (Qn * 128 + brow + n * 16) * 64 + (kk ? cu1 : cu0)];
  };

  f32x4 acc[2][2][4][2] = {};
  bf16x8 af[4][2], af2[4][2], bl[2][2], bh[2][2];
  constexpr int NT = K >> 6;

  stA(0, 0, 0); stB(0, 0, 0); stB(0, 1, 0); stA(0, 1, 0);
  stA(1, 0, 1); stB(1, 0, 1); stB(1, 1, 1);
  asm volatile("s_waitcnt vmcnt(6)" ::: "memory");
  __builtin_amdgcn_s_barrier();

  auto tile_body = [&](int tt, int s1, int s2) {
    const int p = tt & 1;
    // ---- Phase 1: Q00 — read af+bl (12), stage A(tt+1,h1) ----
#pragma unroll
    for (int m = 0; m < 4; ++m) { af[m][0] = ldA(p, 0, m, 0); af[m][1] = ldA(p, 0, m, 1); }
#pragma unroll
    for (int n = 0; n < 2; ++n) { bl[n][0] = ldB(p, 0, n, 0); bl[n][1] = ldB(p, 0, n, 1); }
    if (s1) stA(tt + 1, 1, 1 - p);
    __builtin_amdgcn_sched_barrier(0);
    __builtin_amdgcn_s_barrier();
    asm volatile("s_waitcnt lgkmcnt(0)" ::: "memory");
    __builtin_amdgcn_sched_barrier(0);
    __builtin_amdgcn_s_setprio(1);
    MFMA_QUAD(0, 0, af, bl)
    __builtin_amdgcn_s_setprio(0);
    __builtin_amdgcn_s_barrier();
    // ---- Phase 2: Q01 — read bh (4), stage A(tt+2,h0) ----
#pragma unroll
    for (int n = 0; n < 2; ++n) { bh[n][0] = ldB(p, 1, n, 0); bh[n][1] = ldB(p, 1, n, 1); }
    if (s2) stA(tt + 2, 0, p);
    __builtin_amdgcn_sched_barrier(0);
    __builtin_amdgcn_s_barrier();
    asm volatile("s_waitcnt lgkmcnt(0)" ::: "memory");
    __builtin_amdgcn_sched_barrier(0);
    __builtin_amdgcn_s_setprio(1);
    MFMA_QUAD(0, 1, af, bh)
    __builtin_amdgcn_s_setprio(0);
    __builtin_amdgcn_s_barrier();
    // ---- Phase 3: Q11 — read af2 (8), stage B(tt+2,h0) ----
#pragma unroll
    for (int m = 0; m < 4; ++m) { af2[m][0] = ldA(p, 1, m, 0); af2[m][1] = ldA(p, 1, m, 1); }
    if (s2) stB(tt + 2, 0, p);
    __builtin_amdgcn_sched_barrier(0);
    __builtin_amdgcn_s_barrier();
    asm volatile("s_waitcnt lgkmcnt(0)" ::: "memory");
    __builtin_amdgcn_sched_barrier(0);
    __builtin_amdgcn_s_setprio(1);
    MFMA_QUAD(1, 1, af2, bh)
    __builtin_amdgcn_s_setprio(0);
    __builtin_amdgcn_s_barrier();
    // ---- Phase 4: Q10 — regs only, stage B(tt+2,h1), counted vmcnt ----
    if (s2) stB(tt + 2, 1, p);
    __builtin_amdgcn_sched_barrier(0);
    __builtin_amdgcn_s_barrier();
    __builtin_amdgcn_s_setprio(1);
    MFMA_QUAD(1, 0, af2, bl)
    __builtin_amdgcn_s_setprio(0);
    if (s2) { asm volatile("s_waitcnt vmcnt(6)" ::: "memory"); }
    else if (s1) { asm volatile("s_waitcnt vmcnt(0)" ::: "memory"); }
    __builtin_amdgcn_s_barrier();
  };

  for (int tt = 0; tt < NT - 2; ++tt) tile_body(tt, 1, 1);
  tile_body(NT - 2, 1, 0);
  tile_body(NT - 1, 0, 0);

  // ---------------- epilogue ----------------
  const int row0 = bm * 256 + wq * 64 + hi * 4;
  const int colw = bn * 256 + wn * 64;

  if (EPI == 1) {
#pragma unroll
    for (int Qm = 0; Qm < 2; ++Qm)
#pragma unroll
      for (int m = 0; m < 4; ++m)
#pragma unroll
        for (int r = 0; r < 4; ++r) {
          long row = row0 + Qm * 128 + m * 16 + r;
#pragma unroll
          for (int Qn = 0; Qn < 2; ++Qn)
#pragma unroll
            for (int n = 0; n < 2; ++n) {
              int col = colw + Qn * 32 + n * 16 + lr;
              Cf[row * LDC + col] = acc[Qm][Qn][m][n][r] + bias[col];
            }
        }
    return;
  }

  if (bn < 4) {
    // q: softmax over the wave's 64-col head segment -> qhat[bh][n][64]
    const int h = bn * 4 + wn;
#pragma unroll
    for (int Qm = 0; Qm < 2; ++Qm)
#pragma unroll
      for (int m = 0; m < 4; ++m)
#pragma unroll
        for (int r = 0; r < 4; ++r) {
          float pv[2][2];
          float mx = -1e30f;
#pragma unroll
          for (int Qn = 0; Qn < 2; ++Qn)
#pragma unroll
            for (int nn = 0; nn < 2; ++nn) {
              pv[Qn][nn] = acc[Qm][Qn][m][nn][r] * 0.125f;
              mx = fmaxf(mx, pv[Qn][nn]);
            }
#pragma unroll
          for (int off = 1; off < 16; off <<= 1) mx = fmaxf(mx, __shfl_xor(mx, off));
          float s = 0.f;
#pragma unroll
          for (int Qn = 0; Qn < 2; ++Qn)
#pragma unroll
            for (int nn = 0; nn < 2; ++nn) { pv[Qn][nn] = __expf(pv[Qn][nn] - mx); s += pv[Qn][nn]; }
#pragma unroll
          for (int off = 1; off < 16; off <<= 1) s += __shfl_xor(s, off);
          float inv = 1.0f / s;
          long row = row0 + Qm * 128 + m * 16 + r;
          long base = (((long)(row >> 13) * 16 + h) * NSEQ + (row & 8191)) * 64;
#pragma unroll
          for (int Qn = 0; Qn < 2; ++Qn)
#pragma unroll
            for (int nn = 0; nn < 2; ++nn)
              qh[base + Qn * 32 + nn * 16 + lr] = f2bf(pv[Qn][nn] * inv);
        }
  } else {
    // k: exp + per-batch column sums -> khat[bh][n][64]
    const int h = (bn - 4) * 4 + wn;
    float cs[2][2] = {};
#pragma unroll
    for (int Qm = 0; Qm < 2; ++Qm)
#pragma unroll
      for (int m = 0; m < 4; ++m)
#pragma unroll
        for (int r = 0; r < 4; ++r) {
          long row = row0 + Qm * 128 + m * 16 + r;
          long base = (((long)(row >> 13) * 16 + h) * NSEQ + (row & 8191)) * 64;
#pragma unroll
          for (int Qn = 0; Qn < 2; ++Qn)
#pragma unroll
            for (int nn = 0; nn < 2; ++nn) {
              float pe = __expf(acc[Qm][Qn][m][nn][r]);
              cs[Qn][nn] += pe;
              kh[base + Qn * 32 + nn * 16 + lr] = f2bf(pe);
            }
        }
#pragma unroll
    for (int Qn = 0; Qn < 2; ++Qn)
#pragma unroll
      for (int nn = 0; nn < 2; ++nn) {
        cs[Qn][nn] += __shfl_xor(cs[Qn][nn], 16);
        cs[Qn][nn] += __shfl_xor(cs[Qn][nn], 32);
      }
    if (lane < 16) {
      int b = bm >> 5;
#pragma unroll
      for (int Qn = 0; Qn < 2; ++Qn)
#pragma unroll
        for (int nn = 0; nn < 2; ++nn)
          atomicAdd(&S[b * DMODEL + h * 64 + Qn * 32 + nn * 16 + lane], cs[Qn][nn]);
    }
  }
}

// ============ ctx partial via MFMA: ctx[bh][d][e] = sum_n q[n][d] k[n][e] ============
__global__ __launch_bounds__(256) void k_ctx(const u16* __restrict__ qhat,
                                             const u16* __restrict__ khat,
                                             float* __restrict__ ctx_part) {
  __shared__ __align__(16) u16 smu[2 * 17408];  // buf{0,1} x (qT 8704 | kT 8704) u16
  const int bh = blockIdx.x, nc = blockIdx.y;
  const int t = threadIdx.x;
  const int lane = t & 63;
  const int ww = t >> 6;
  const int lr = lane & 15;
  const int hi = lane >> 4;

  const int isK = t >> 7;
  const int u = t & 127;
  const int ng = u >> 3;
  const int dc = u & 7;
  const u16* srcm = (isK ? khat : qhat) + (long)bh * NSEQ * 64;

  f32x4 acc[4][4] = {};
  short8 v[8];

  auto load_stage = [&](int s) {
    long nb = (long)nc * 1024 + s * 128;
    const u16* src = srcm + (nb + ng * 8) * 64 + dc * 8;
#pragma unroll
    for (int i = 0; i < 8; ++i) v[i] = *(const short8*)(src + i * 64);
  };
  auto write_stage = [&](int s) {
    const int buf = s & 1;
    u16* dst0 = &smu[buf * 17408 + isK * 8704 + (dc * 8) * 136 + (ng ^ dc) * 8];
#pragma unroll
    for (int j = 0; j < 8; ++j) {
      short8 o;
#pragma unroll
      for (int i = 0; i < 8; ++i) o[i] = v[i][j];
      *(short8*)(dst0 + j * 136) = o;
    }
  };
  auto compute = [&](int s) {
    const int buf = s & 1;
    const int g = ww * 4 + hi;
    const u16* qb = &smu[buf * 17408];
    const u16* kb = qb + 8704;
    bf16x8 a[4], b[4];
#pragma unroll
    for (int dt = 0; dt < 4; ++dt) {
      int d = dt * 16 + lr;
      a[dt] = *(const bf16x8*)(qb + d * 136 + (g ^ ((d >> 3) & 7)) * 8);
    }
#pragma unroll
    for (int et = 0; et < 4; ++et) {
      int d = et * 16 + lr;
      b[et] = *(const bf16x8*)(kb + d * 136 + (g ^ ((d >> 3) & 7)) * 8);
    }
#pragma unroll
    for (int dt = 0; dt < 4; ++dt)
#pragma unroll
      for (int et = 0; et < 4; ++et)
        acc[dt][et] = __builtin_amdgcn_mfma_f32_16x16x32_bf16(a[dt], b[et], acc[dt][et], 0, 0, 0);
  };

  load_stage(0);
  write_stage(0);
  __syncthreads();
  for (int s = 0; s < 8; ++s) {
    if (s < 7) load_stage(s + 1);
    compute(s);
    if (s < 7) write_stage(s + 1);
    __syncthreads();
  }

  float* smf = (float*)smu;
#pragma unroll
  for (int dt = 0; dt < 4; ++dt)
#pragma unroll
    for (int et = 0; et < 4; ++et)
      *(f32x4*)&smf[ww * 4096 + (dt * 4 + hi) * 256 + (et * 16 + lr) * 4] = acc[dt][et];
  __syncthreads();
  float* op = ctx_part + ((long)nc * 64 + bh) * 4096;
#pragma unroll
  for (int rep = 0; rep < 4; ++rep) {
    int p4 = rep * 1024 + t * 4;
    f32x4 sum = *(const f32x4*)&smf[p4];
    sum += *(const f32x4*)&smf[4096 + p4];
    sum += *(const f32x4*)&smf[8192 + p4];
    sum += *(const f32x4*)&smf[12288 + p4];
    *(f32x4*)&op[p4] = sum;
  }
}

// ---------------- reduce partials + normalize by S -> ctxn bf16 [bh][d][e] ----------------
__global__ __launch_bounds__(256) void k_cred(const float* __restrict__ ctx_part,
                                              const float* __restrict__ S,
                                              u16* __restrict__ ctxn) {
  const int bh = blockIdx.x;
  const int b = bh >> 4, h = bh & 15;
  const int p = blockIdx.y * 256 + threadIdx.x;  // 0..4095 phys
  float s = 0.f;
#pragma unroll
  for (int nc = 0; nc < 8; ++nc)
    s += ctx_part[((long)nc * 64 + bh) * 4096 + p];
  int d = (p >> 8) * 4 + (p & 3);
  int e = (p >> 2) & 63;
  ctxn[(long)bh * 4096 + d * 64 + e] = f2bf(s / S[b * DMODEL + h * 64 + e]);
}

// ---------------- CtT[b][eo][h64+d] = sum_e woutT[eo][h64+e] * ctxn[bh][d][e] ----------------
__global__ __launch_bounds__(256) void k_ct(const u16* __restrict__ woutT,
                                            const u16* __restrict__ ctxn,
                                            u16* __restrict__ ctT) {
  __shared__ __align__(16) u16 cb[64 * 72];
  const int b = blockIdx.x, h = blockIdx.y;
  const int t = threadIdx.x, lane = t & 63, ww = t >> 6;
  const int lr = lane & 15, hi = lane >> 4;
  {
    const u16* src = ctxn + ((long)(b * 16 + h)) * 4096 + t * 16;
    int row = t >> 2, col = (t & 3) * 16;
    *(short8*)(cb + row * 72 + col) = *(const short8*)src;
    *(short8*)(cb + row * 72 + col + 8) = *(const short8*)(src + 8);
  }
  __syncthreads();
  bf16x8 bfrag[4][2];
#pragma unroll
  for (int n = 0; n < 4; ++n)
#pragma unroll
    for (int kk = 0; kk < 2; ++kk)
      bfrag[n][kk] = *(const bf16x8*)(cb + (n * 16 + lr) * 72 + kk * 32 + hi * 8);
  const int row0 = ww * 256;
  u16* outp = ctT + ((long)b * 1024) * 1024 + (long)h * 64;
#pragma unroll
  for (int m = 0; m < 16; ++m) {
    int arow = row0 + m * 16 + lr;
    const u16* ap = woutT + (long)arow * DMODEL + h * 64;
    bf16x8 a0 = *(const bf16x8*)(ap + hi * 8);
    bf16x8 a1 = *(const bf16x8*)(ap + 32 + hi * 8);
    f32x4 accr[4] = {};
#pragma unroll
    for (int n = 0; n < 4; ++n)
      accr[n] = __builtin_amdgcn_mfma_f32_16x16x32_bf16(a1, bfrag[n][1],
                __builtin_amdgcn_mfma_f32_16x16x32_bf16(a0, bfrag[n][0], accr[n], 0, 0, 0), 0, 0, 0);
#pragma unroll
    for (int n = 0; n < 4; ++n)
#pragma unroll
      for (int r = 0; r < 4; ++r)
        outp[(long)(row0 + m * 16 + hi * 4 + r) * DMODEL + n * 16 + lr] = f2bf(accr[n][r]);
  }
}

// ---------------- 128x128 bf16 GEMM: C[M][N] = A[M][K]*B^T[N][K], bf16 out ----------------
__global__ __launch_bounds__(256) void k_wc(const u16* __restrict__ A,
                                            const u16* __restrict__ B,
                                            u16* __restrict__ Cb) {
  __shared__ __align__(16) u16 As[128 * 32];
  __shared__ __align__(16) u16 Bs[128 * 32];
  const int K = 1024, ldc = 1024;
  const int t = threadIdx.x;
  const int lane = t & 63;
  const int w = t >> 6;
  const int wm = w >> 1, wn = w & 1;
  const long bm = blockIdx.x, bn = blockIdx.y;

  f32x4 acc[4][4] = {};

  const u16* Ag = A + bm * 128 * (long)K;
  const u16* Bg = B + bn * 128 * (long)K;
  const int r0 = t >> 2;
  const int s0 = (t & 3) * 8;
  const int ko = (lane >> 4) * 8;
  const int lr = lane & 15;

  for (int kt = 0; kt < K; kt += 32) {
    short8 a0 = *(const short8*)(Ag + (long)r0 * K + kt + s0);
    short8 a1 = *(const short8*)(Ag + (long)(r0 + 64) * K + kt + s0);
    short8 b0 = *(const short8*)(Bg + (long)r0 * K + kt + s0);
    short8 b1 = *(const short8*)(Bg + (long)(r0 + 64) * K + kt + s0);
    __syncthreads();
    *(short8*)(As + r0 * 32 + s0) = a0;
    *(short8*)(As + (r0 + 64) * 32 + s0) = a1;
    *(short8*)(Bs + r0 * 32 + s0) = b0;
    *(short8*)(Bs + (r0 + 64) * 32 + s0) = b1;
    __syncthreads();
    bf16x8 af[4], bfr[4];
#pragma unroll
    for (int m = 0; m < 4; ++m)
      af[m] = *(const bf16x8*)(As + (wm * 64 + m * 16 + lr) * 32 + ko);
#pragma unroll
    for (int n = 0; n < 4; ++n)
      bfr[n] = *(const bf16x8*)(Bs + (wn * 64 + n * 16 + lr) * 32 + ko);
#pragma unroll
    for (int m = 0; m < 4; ++m)
#pragma unroll
      for (int n = 0; n < 4; ++n)
        acc[m][n] = __builtin_amdgcn_mfma_f32_16x16x32_bf16(af[m], bfr[n], acc[m][n], 0, 0, 0);
  }

  const int row_base = (int)bm * 128 + wm * 64 + (lane >> 4) * 4;
  const int col_base = (int)bn * 128 + wn * 64 + lr;
#pragma unroll
  for (int m = 0; m < 4; ++m)
#pragma unroll
    for (int n = 0; n < 4; ++n)
#pragma unroll
      for (int r = 0; r < 4; ++r)
        Cb[(long)(row_base + m * 16 + r) * ldc + col_base + n * 16] = f2bf(acc[m][n][r]);
}

// ---------------- launch ----------------
extern "C" void kernel_launch(void* const* d_in, const int* in_sizes, int n_in,
                              void* d_out, int out_size, void* d_ws, size_t ws_size,
                              hipStream_t stream) {
  const float* x = (const float*)d_in[0];
  const float* w_qkv = (const float*)d_in[1];
  const float* w_out = (const float*)d_in[2];
  const float* b_out = (const float*)d_in[3];
  float* out = (float*)d_out;
  char* ws = (char*)d_ws;

  u16* xb      = (u16*)(ws + 0);                 // 64 MB
  u16* wqkvT   = (u16*)(ws + 67108864L);         // 6 MB (qk cols only used)
  u16* woutT   = (u16*)(ws + 73400320L);         // 2 MB
  u16* wvb     = (u16*)(ws + 75497472L);         // 2 MB
  u16* qhat    = (u16*)(ws + 77594624L);         // 64 MB
  u16* khat    = (u16*)(ws + 144703488L);        // 64 MB
  float* S     = (float*)(ws + 211812352L);      // 16 KB
  u16* ctxn    = (u16*)(ws + 211828736L);        // 512 KB
  float* cpart = (float*)(ws + 212353024L);      // 8 MB
  u16* ctT     = (u16*)(ws + 220741632L);        // 8 MB
  u16* wcT     = (u16*)(ws + 229130240L);        // 8 MB

  hipMemsetAsync(S, 0, 16384, stream);

  k_convert<<<32768, 256, 0, stream>>>(x, xb, (long)MROWS * DMODEL);
  k_cv<<<1024, 256, 0, stream>>>(w_qkv, wvb);
  k_transpose<<<dim3(64, 32), dim3(32, 8), 0, stream>>>(w_qkv, wqkvT, DMODEL, QKVCOLS);
  k_transpose<<<dim3(32, 32), dim3(32, 8), 0, stream>>>(w_out, woutT, DMODEL, DMODEL);

  // qk GEMM (N=2048) with fused q-softmax / k-exp epilogue -> qhat/khat
  k_gemm256<0, DMODEL, DMODEL, 8, QKVCOLS, 0L>
      <<<dim3((MROWS / 256) * (2048 / 256)), 512, 0, stream>>>(
      xb, wqkvT, nullptr, qhat, khat, nullptr, S);

  k_ctx<<<dim3(64, 8), 256, 0, stream>>>(qhat, khat, cpart);
  k_cred<<<dim3(64, 16), 256, 0, stream>>>(cpart, S, ctxn);
  k_ct<<<dim3(4, 16), 256, 0, stream>>>(woutT, ctxn, ctT);
  // WcT[b] = CtT[b] @ Wv^T  (M=4096 stacked, N=1024, K=1024)
  k_wc<<<dim3(32, 8), 256, 0, stream>>>(ctT, wvb, wcT);

  // out GEMM: out = xb x WcT[b]^T + bias, fp32 store
  k_gemm256<1, DMODEL, DMODEL, 4, DMODEL, (long)DMODEL * DMODEL>
      <<<dim3((MROWS / 256) * (DMODEL / 256)), 512, 0, stream>>>(
      xb, wcT, b_out, nullptr, nullptr, out, nullptr);
}

// Round 13
// 331.733 us; speedup vs baseline: 1.0141x; 1.0141x over previous
//
#include <hip/hip_runtime.h>

typedef unsigned short u16;
typedef __attribute__((ext_vector_type(8))) short short8;
typedef __attribute__((ext_vector_type(4))) unsigned short u16x4;
typedef __attribute__((ext_vector_type(8))) __bf16 bf16x8;
typedef __attribute__((ext_vector_type(4))) float f32x4;

#define B_SZ 4
#define NSEQ 8192
#define DMODEL 1024
#define MROWS 32768
#define QKVCOLS 3072

static __device__ __forceinline__ u16 f2bf(float f) {
  unsigned u = __builtin_bit_cast(unsigned, f);
  u += 0x7fffu + ((u >> 16) & 1u);
  return (u16)(u >> 16);
}
static __device__ __forceinline__ float bf2f(u16 h) {
  return __builtin_bit_cast(float, ((unsigned)h) << 16);
}
static __device__ __forceinline__ void gload16(const u16* g, u16* l) {
  __builtin_amdgcn_global_load_lds(
      (const __attribute__((address_space(1))) unsigned*)g,
      (__attribute__((address_space(3))) unsigned*)l, 16, 0, 0);
}

// ---------------- fp32 -> bf16 convert ----------------
__global__ __launch_bounds__(256) void k_convert(const float* __restrict__ in,
                                                 u16* __restrict__ out, long n) {
  long i = ((long)blockIdx.x * 256 + threadIdx.x) * 4;
  if (i >= n) return;
  f32x4 v = *(const f32x4*)(in + i);
  u16x4 o;
  o[0] = f2bf(v[0]); o[1] = f2bf(v[1]); o[2] = f2bf(v[2]); o[3] = f2bf(v[3]);
  *(u16x4*)(out + i) = o;
}

// ---------------- wvb[i][k] = bf16(w_qkv[i][2048+k])  (1024x1024) ----------------
__global__ __launch_bounds__(256) void k_cv(const float* __restrict__ wq,
                                            u16* __restrict__ wvb) {
  int idx = (blockIdx.x * 256 + threadIdx.x) * 4;
  int i = idx >> 10, k = idx & 1023;
  f32x4 v = *(const f32x4*)(wq + (long)i * QKVCOLS + 2048 + k);
  u16x4 o;
  o[0] = f2bf(v[0]); o[1] = f2bf(v[1]); o[2] = f2bf(v[2]); o[3] = f2bf(v[3]);
  *(u16x4*)(wvb + idx) = o;
}

// ---------------- transpose fp32[R][C] -> bf16[C][R] ----------------
__global__ __launch_bounds__(256) void k_transpose(const float* __restrict__ in,
                                                   u16* __restrict__ out, int R, int C) {
  __shared__ float tile[32][33];
  int c0 = blockIdx.x * 32, r0 = blockIdx.y * 32;
  int tx = threadIdx.x, ty = threadIdx.y;  // (32, 8)
#pragma unroll
  for (int j = 0; j < 32; j += 8)
    tile[ty + j][tx] = in[(long)(r0 + ty + j) * C + c0 + tx];
  __syncthreads();
#pragma unroll
  for (int j = 0; j < 32; j += 8)
    out[(long)(c0 + ty + j) * R + r0 + tx] = f2bf(tile[tx][ty + j]);
}

// ============ 256x256 3-phase bf16 GEMM: C = A[M][K] * B^T[N][K] ============
// EPI 0: qk fused epilogue -> qhat/khat head-major [bh][n][64] (+softmax / exp+colsum)
// EPI 1: fp32 + bias to Cf
#define MFMA_QUAD(Qm, Qn, A_, B_)                                              \
  _Pragma("unroll") for (int m = 0; m < 4; ++m)                                \
  _Pragma("unroll") for (int n = 0; n < 2; ++n)                                \
    acc[Qm][Qn][m][n] = __builtin_amdgcn_mfma_f32_16x16x32_bf16(A_[m][1], B_[n][1], \
        __builtin_amdgcn_mfma_f32_16x16x32_bf16(A_[m][0], B_[n][0], acc[Qm][Qn][m][n], 0, 0, 0), 0, 0, 0);

template <int EPI, int K, int LDA, int NBN, int LDC, long BSTR>
__global__ __launch_bounds__(512, 2) void k_gemm256(
    const u16* __restrict__ A, const u16* __restrict__ Bp,
    const float* __restrict__ bias, u16* __restrict__ qh,
    u16* __restrict__ kh, float* __restrict__ Cf, float* __restrict__ S) {
  __shared__ __align__(16) u16 sm[65536];  // A0|A1|B0|B1, 16384 u16 each
  const int t = threadIdx.x;
  const int lane = t & 63;
  const int w = t >> 6;       // 0..7
  const int wq = w >> 2;      // row-half within quadrant
  const int wn = w & 3;       // col group
  const int lr = lane & 15;
  const int hi = lane >> 4;
  const int l3 = lane >> 3;

  // XCD swizzle + bm-group-of-8
  const int nwg = gridDim.x;
  const int bid = blockIdx.x;
  const int swz = (bid & 7) * (nwg >> 3) + (bid >> 3);
  const int per = 8 * NBN;
  const int grp = swz / per, rem = swz % per;
  const int bm = grp * 8 + (rem & 7);
  const int bn = rem / 8;

  const u16* B = Bp + (long)(bm >> 5) * BSTR;
  const int gcol = ((lane & 7) ^ l3) * 8;  // swizzled k-offset (elements)

  auto stA = [&](int tile, int half, int buf) {
    u16* dst = &sm[buf * 16384 + (half * 128 + w * 16) * 64];
    const u16* g = A + ((long)(bm * 256 + half * 128 + w * 16 + l3)) * LDA + tile * 64 + gcol;
    gload16(g, dst);
    gload16(g + 8 * (long)LDA, dst + 8 * 64);
  };
  auto stB = [&](int tile, int half, int buf) {
#pragma unroll
    for (int L = 0; L < 2; ++L) {
      int base = half * 128 + w * 16 + L * 8;  // LDS B row base
      int grow = bn * 256 + ((base >> 5) & 3) * 64 + half * 32 + (base & 31) + l3;
      const u16* g = B + (long)grow * K + tile * 64 + gcol;
      gload16(g, &sm[32768 + buf * 16384 + base * 64]);
    }
  };

  const int su = (lr & 7) << 3;
  const int cu0 = (hi * 8) ^ su;         // kk=0 swizzled col (u16 units)
  const int cu1 = (32 + hi * 8) ^ su;    // kk=1
  const int arow = wq * 64 + lr;
  const int brow = wn * 32 + lr;

  auto ldA = [&](int buf, int Qm, int m, int kk) -> bf16x8 {
    return *(const bf16x8*)&sm[buf * 16384 + (Qm * 128 + arow + m * 16) * 64 + (kk ? cu1 : cu0)];
  };
  auto ldB = [&](int buf, int Qn, int n, int kk) -> bf16x8 {
    return *(const bf16x8*)&sm[32768 + buf * 16384 + (Qn * 128 + brow + n * 16) * 64 + (kk ? cu1 : cu0)];
  };

  f32x4 acc[2][2][4][2] = {};
  bf16x8 af[4][2], af2[4][2], bl[2][2], bh[2][2];
  constexpr int NT = K >> 6;

  stA(0, 0, 0); stB(0, 0, 0); stB(0, 1, 0); stA(0, 1, 0);
  stA(1, 0, 1); stB(1, 0, 1); stB(1, 1, 1);
  asm volatile("s_waitcnt vmcnt(6)" ::: "memory");
  __builtin_amdgcn_s_barrier();

  auto tile_body = [&](int tt, int s1, int s2) {
    const int p = tt & 1;
#pragma unroll
    for (int m = 0; m < 4; ++m) { af[m][0] = ldA(p, 0, m, 0); af[m][1] = ldA(p, 0, m, 1); }
#pragma unroll
    for (int n = 0; n < 2; ++n) { bl[n][0] = ldB(p, 0, n, 0); bl[n][1] = ldB(p, 0, n, 1); }
    __builtin_amdgcn_sched_barrier(0);
#pragma unroll
    for (int n = 0; n < 2; ++n) { bh[n][0] = ldB(p, 1, n, 0); bh[n][1] = ldB(p, 1, n, 1); }
    __builtin_amdgcn_sched_barrier(0);
    if (s1) stA(tt + 1, 1, 1 - p);
    __builtin_amdgcn_sched_barrier(0);
    asm volatile("s_waitcnt lgkmcnt(4)" ::: "memory");
    __builtin_amdgcn_sched_barrier(0);
    __builtin_amdgcn_s_setprio(1);
    MFMA_QUAD(0, 0, af, bl)
    __builtin_amdgcn_s_setprio(0);
    __builtin_amdgcn_s_barrier();
#pragma unroll
    for (int m = 0; m < 4; ++m) { af2[m][0] = ldA(p, 1, m, 0); af2[m][1] = ldA(p, 1, m, 1); }
    __builtin_amdgcn_sched_barrier(0);
    if (s2) stA(tt + 2, 0, p);
    __builtin_amdgcn_sched_barrier(0);
    asm volatile("s_waitcnt lgkmcnt(8)" ::: "memory");
    __builtin_amdgcn_sched_barrier(0);
    __builtin_amdgcn_s_setprio(1);
    MFMA_QUAD(0, 1, af, bh)
    __builtin_amdgcn_s_setprio(0);
    __builtin_amdgcn_s_barrier();
    if (s2) { stB(tt + 2, 0, p); stB(tt + 2, 1, p); }
    __builtin_amdgcn_sched_barrier(0);
    asm volatile("s_waitcnt lgkmcnt(0)" ::: "memory");
    __builtin_amdgcn_sched_barrier(0);
    __builtin_amdgcn_s_setprio(1);
    MFMA_QUAD(1, 1, af2, bh)
    MFMA_QUAD(1, 0, af2, bl)
    __builtin_amdgcn_s_setprio(0);
    if (s2) { asm volatile("s_waitcnt vmcnt(6)" ::: "memory"); }
    else if (s1) { asm volatile("s_waitcnt vmcnt(0)" ::: "memory"); }
    __builtin_amdgcn_s_barrier();
  };

  for (int tt = 0; tt < NT - 2; ++tt) tile_body(tt, 1, 1);
  tile_body(NT - 2, 1, 0);
  tile_body(NT - 1, 0, 0);

  // ---------------- epilogue ----------------
  const int row0 = bm * 256 + wq * 64 + hi * 4;
  const int colw = bn * 256 + wn * 64;

  if (EPI == 1) {
#pragma unroll
    for (int Qm = 0; Qm < 2; ++Qm)
#pragma unroll
      for (int m = 0; m < 4; ++m)
#pragma unroll
        for (int r = 0; r < 4; ++r) {
          long row = row0 + Qm * 128 + m * 16 + r;
#pragma unroll
          for (int Qn = 0; Qn < 2; ++Qn)
#pragma unroll
            for (int n = 0; n < 2; ++n) {
              int col = colw + Qn * 32 + n * 16 + lr;
              Cf[row * LDC + col] = acc[Qm][Qn][m][n][r] + bias[col];
            }
        }
    return;
  }

  if (bn < 4) {
    // q: softmax over the wave's 64-col head segment -> qhat[bh][n][64]
    const int h = bn * 4 + wn;
#pragma unroll
    for (int Qm = 0; Qm < 2; ++Qm)
#pragma unroll
      for (int m = 0; m < 4; ++m)
#pragma unroll
        for (int r = 0; r < 4; ++r) {
          float pv[2][2];
          float mx = -1e30f;
#pragma unroll
          for (int Qn = 0; Qn < 2; ++Qn)
#pragma unroll
            for (int nn = 0; nn < 2; ++nn) {
              pv[Qn][nn] = acc[Qm][Qn][m][nn][r] * 0.125f;
              mx = fmaxf(mx, pv[Qn][nn]);
            }
#pragma unroll
          for (int off = 1; off < 16; off <<= 1) mx = fmaxf(mx, __shfl_xor(mx, off));
          float s = 0.f;
#pragma unroll
          for (int Qn = 0; Qn < 2; ++Qn)
#pragma unroll
            for (int nn = 0; nn < 2; ++nn) { pv[Qn][nn] = __expf(pv[Qn][nn] - mx); s += pv[Qn][nn]; }
#pragma unroll
          for (int off = 1; off < 16; off <<= 1) s += __shfl_xor(s, off);
          float inv = 1.0f / s;
          long row = row0 + Qm * 128 + m * 16 + r;
          long base = (((long)(row >> 13) * 16 + h) * NSEQ + (row & 8191)) * 64;
#pragma unroll
          for (int Qn = 0; Qn < 2; ++Qn)
#pragma unroll
            for (int nn = 0; nn < 2; ++nn)
              qh[base + Qn * 32 + nn * 16 + lr] = f2bf(pv[Qn][nn] * inv);
        }
  } else {
    // k: exp + per-batch column sums -> khat[bh][n][64]
    const int h = (bn - 4) * 4 + wn;
    float cs[2][2] = {};
#pragma unroll
    for (int Qm = 0; Qm < 2; ++Qm)
#pragma unroll
      for (int m = 0; m < 4; ++m)
#pragma unroll
        for (int r = 0; r < 4; ++r) {
          long row = row0 + Qm * 128 + m * 16 + r;
          long base = (((long)(row >> 13) * 16 + h) * NSEQ + (row & 8191)) * 64;
#pragma unroll
          for (int Qn = 0; Qn < 2; ++Qn)
#pragma unroll
            for (int nn = 0; nn < 2; ++nn) {
              float pe = __expf(acc[Qm][Qn][m][nn][r]);
              cs[Qn][nn] += pe;
              kh[base + Qn * 32 + nn * 16 + lr] = f2bf(pe);
            }
        }
#pragma unroll
    for (int Qn = 0; Qn < 2; ++Qn)
#pragma unroll
      for (int nn = 0; nn < 2; ++nn) {
        cs[Qn][nn] += __shfl_xor(cs[Qn][nn], 16);
        cs[Qn][nn] += __shfl_xor(cs[Qn][nn], 32);
      }
    if (lane < 16) {
      int b = bm >> 5;
#pragma unroll
      for (int Qn = 0; Qn < 2; ++Qn)
#pragma unroll
        for (int nn = 0; nn < 2; ++nn)
          atomicAdd(&S[b * DMODEL + h * 64 + Qn * 32 + nn * 16 + lane], cs[Qn][nn]);
    }
  }
}

// ============ ctx partial via MFMA: ctx[bh][d][e] = sum_n q[n][d] k[n][e] ============
__global__ __launch_bounds__(256) void k_ctx(const u16* __restrict__ qhat,
                                             const u16* __restrict__ khat,
                                             float* __restrict__ ctx_part) {
  __shared__ __align__(16) u16 smu[2 * 17408];  // buf{0,1} x (qT 8704 | kT 8704) u16
  const int bh = blockIdx.x, nc = blockIdx.y;
  const int t = threadIdx.x;
  const int lane = t & 63;
  const int ww = t >> 6;
  const int lr = lane & 15;
  const int hi = lane >> 4;

  const int isK = t >> 7;
  const int u = t & 127;
  const int ng = u >> 3;
  const int dc = u & 7;
  const u16* srcm = (isK ? khat : qhat) + (long)bh * NSEQ * 64;

  f32x4 acc[4][4] = {};
  short8 v[8];

  auto load_stage = [&](int s) {
    long nb = (long)nc * 1024 + s * 128;
    const u16* src = srcm + (nb + ng * 8) * 64 + dc * 8;
#pragma unroll
    for (int i = 0; i < 8; ++i) v[i] = *(const short8*)(src + i * 64);
  };
  auto write_stage = [&](int s) {
    const int buf = s & 1;
    u16* dst0 = &smu[buf * 17408 + isK * 8704 + (dc * 8) * 136 + (ng ^ dc) * 8];
#pragma unroll
    for (int j = 0; j < 8; ++j) {
      short8 o;
#pragma unroll
      for (int i = 0; i < 8; ++i) o[i] = v[i][j];
      *(short8*)(dst0 + j * 136) = o;
    }
  };
  auto compute = [&](int s) {
    const int buf = s & 1;
    const int g = ww * 4 + hi;
    const u16* qb = &smu[buf * 17408];
    const u16* kb = qb + 8704;
    bf16x8 a[4], b[4];
#pragma unroll
    for (int dt = 0; dt < 4; ++dt) {
      int d = dt * 16 + lr;
      a[dt] = *(const bf16x8*)(qb + d * 136 + (g ^ ((d >> 3) & 7)) * 8);
    }
#pragma unroll
    for (int et = 0; et < 4; ++et) {
      int d = et * 16 + lr;
      b[et] = *(const bf16x8*)(kb + d * 136 + (g ^ ((d >> 3) & 7)) * 8);
    }
#pragma unroll
    for (int dt = 0; dt < 4; ++dt)
#pragma unroll
      for (int et = 0; et < 4; ++et)
        acc[dt][et] = __builtin_amdgcn_mfma_f32_16x16x32_bf16(a[dt], b[et], acc[dt][et], 0, 0, 0);
  };

  load_stage(0);
  write_stage(0);
  __syncthreads();
  for (int s = 0; s < 8; ++s) {
    if (s < 7) load_stage(s + 1);
    compute(s);
    if (s < 7) write_stage(s + 1);
    __syncthreads();
  }

  float* smf = (float*)smu;
#pragma unroll
  for (int dt = 0; dt < 4; ++dt)
#pragma unroll
    for (int et = 0; et < 4; ++et)
      *(f32x4*)&smf[ww * 4096 + (dt * 4 + hi) * 256 + (et * 16 + lr) * 4] = acc[dt][et];
  __syncthreads();
  float* op = ctx_part + ((long)nc * 64 + bh) * 4096;
#pragma unroll
  for (int rep = 0; rep < 4; ++rep) {
    int p4 = rep * 1024 + t * 4;
    f32x4 sum = *(const f32x4*)&smf[p4];
    sum += *(const f32x4*)&smf[4096 + p4];
    sum += *(const f32x4*)&smf[8192 + p4];
    sum += *(const f32x4*)&smf[12288 + p4];
    *(f32x4*)&op[p4] = sum;
  }
}

// ---- fused: reduce cpart + normalize by S -> LDS tile; then CtT = wout^T x ctxn ----
// CtT[b][eo][h64+d] = sum_e woutT[eo][h64+e] * ctxn[bh][d][e]; grid (4, 16)
__global__ __launch_bounds__(256) void k_ct(const u16* __restrict__ woutT,
                                            const float* __restrict__ cpart,
                                            const float* __restrict__ S,
                                            u16* __restrict__ ctT) {
  __shared__ __align__(16) u16 cb[64 * 72];
  const int b = blockIdx.x, h = blockIdx.y;
  const int bh = b * 16 + h;
  const int t = threadIdx.x, lane = t & 63, ww = t >> 6;
  const int lr = lane & 15, hi = lane >> 4;
  // reduce 8 slices of cpart (phys layout) + normalize -> cb[d][e]
  for (int p = t; p < 4096; p += 256) {
    float s = 0.f;
#pragma unroll
    for (int nc = 0; nc < 8; ++nc)
      s += cpart[((long)nc * 64 + bh) * 4096 + p];
    int d = (p >> 8) * 4 + (p & 3);
    int e = (p >> 2) & 63;
    cb[d * 72 + e] = f2bf(s / S[b * DMODEL + h * 64 + e]);
  }
  __syncthreads();
  bf16x8 bfrag[4][2];
#pragma unroll
  for (int n = 0; n < 4; ++n)
#pragma unroll
    for (int kk = 0; kk < 2; ++kk)
      bfrag[n][kk] = *(const bf16x8*)(cb + (n * 16 + lr) * 72 + kk * 32 + hi * 8);
  const int row0 = ww * 256;
  u16* outp = ctT + ((long)b * 1024) * 1024 + (long)h * 64;
#pragma unroll
  for (int m = 0; m < 16; ++m) {
    int arow = row0 + m * 16 + lr;
    const u16* ap = woutT + (long)arow * DMODEL + h * 64;
    bf16x8 a0 = *(const bf16x8*)(ap + hi * 8);
    bf16x8 a1 = *(const bf16x8*)(ap + 32 + hi * 8);
    f32x4 accr[4] = {};
#pragma unroll
    for (int n = 0; n < 4; ++n)
      accr[n] = __builtin_amdgcn_mfma_f32_16x16x32_bf16(a1, bfrag[n][1],
                __builtin_amdgcn_mfma_f32_16x16x32_bf16(a0, bfrag[n][0], accr[n], 0, 0, 0), 0, 0, 0);
#pragma unroll
    for (int n = 0; n < 4; ++n)
#pragma unroll
      for (int r = 0; r < 4; ++r)
        outp[(long)(row0 + m * 16 + hi * 4 + r) * DMODEL + n * 16 + lr] = f2bf(accr[n][r]);
  }
}

// ---------------- 128x128 bf16 GEMM: C[M][N] = A[M][K]*B^T[N][K], bf16 out ----------------
__global__ __launch_bounds__(256) void k_wc(const u16* __restrict__ A,
                                            const u16* __restrict__ B,
                                            u16* __restrict__ Cb) {
  __shared__ __align__(16) u16 As[128 * 32];
  __shared__ __align__(16) u16 Bs[128 * 32];
  const int K = 1024, ldc = 1024;
  const int t = threadIdx.x;
  const int lane = t & 63;
  const int w = t >> 6;
  const int wm = w >> 1, wn = w & 1;
  const long bm = blockIdx.x, bn = blockIdx.y;

  f32x4 acc[4][4] = {};

  const u16* Ag = A + bm * 128 * (long)K;
  const u16* Bg = B + bn * 128 * (long)K;
  const int r0 = t >> 2;
  const int s0 = (t & 3) * 8;
  const int ko = (lane >> 4) * 8;
  const int lr = lane & 15;

  for (int kt = 0; kt < K; kt += 32) {
    short8 a0 = *(const short8*)(Ag + (long)r0 * K + kt + s0);
    short8 a1 = *(const short8*)(Ag + (long)(r0 + 64) * K + kt + s0);
    short8 b0 = *(const short8*)(Bg + (long)r0 * K + kt + s0);
    short8 b1 = *(const short8*)(Bg + (long)(r0 + 64) * K + kt + s0);
    __syncthreads();
    *(short8*)(As + r0 * 32 + s0) = a0;
    *(short8*)(As + (r0 + 64) * 32 + s0) = a1;
    *(short8*)(Bs + r0 * 32 + s0) = b0;
    *(short8*)(Bs + (r0 + 64) * 32 + s0) = b1;
    __syncthreads();
    bf16x8 af[4], bfr[4];
#pragma unroll
    for (int m = 0; m < 4; ++m)
      af[m] = *(const bf16x8*)(As + (wm * 64 + m * 16 + lr) * 32 + ko);
#pragma unroll
    for (int n = 0; n < 4; ++n)
      bfr[n] = *(const bf16x8*)(Bs + (wn * 64 + n * 16 + lr) * 32 + ko);
#pragma unroll
    for (int m = 0; m < 4; ++m)
#pragma unroll
      for (int n = 0; n < 4; ++n)
        acc[m][n] = __builtin_amdgcn_mfma_f32_16x16x32_bf16(af[m], bfr[n], acc[m][n], 0, 0, 0);
  }

  const int row_base = (int)bm * 128 + wm * 64 + (lane >> 4) * 4;
  const int col_base = (int)bn * 128 + wn * 64 + lr;
#pragma unroll
  for (int m = 0; m < 4; ++m)
#pragma unroll
    for (int n = 0; n < 4; ++n)
#pragma unroll
      for (int r = 0; r < 4; ++r)
        Cb[(long)(row_base + m * 16 + r) * ldc + col_base + n * 16] = f2bf(acc[m][n][r]);
}

// ---------------- launch ----------------
extern "C" void kernel_launch(void* const* d_in, const int* in_sizes, int n_in,
                              void* d_out, int out_size, void* d_ws, size_t ws_size,
                              hipStream_t stream) {
  const float* x = (const float*)d_in[0];
  const float* w_qkv = (const float*)d_in[1];
  const float* w_out = (const float*)d_in[2];
  const float* b_out = (const float*)d_in[3];
  float* out = (float*)d_out;
  char* ws = (char*)d_ws;

  u16* xb      = (u16*)(ws + 0);                 // 64 MB
  u16* wqkvT   = (u16*)(ws + 67108864L);         // 6 MB (qk cols only used)
  u16* woutT   = (u16*)(ws + 73400320L);         // 2 MB
  u16* wvb     = (u16*)(ws + 75497472L);         // 2 MB
  u16* qhat    = (u16*)(ws + 77594624L);         // 64 MB
  u16* khat    = (u16*)(ws + 144703488L);        // 64 MB
  float* S     = (float*)(ws + 211812352L);      // 16 KB
  float* cpart = (float*)(ws + 212353024L);      // 8 MB
  u16* ctT     = (u16*)(ws + 220741632L);        // 8 MB
  u16* wcT     = (u16*)(ws + 229130240L);        // 8 MB

  hipMemsetAsync(S, 0, 16384, stream);

  k_convert<<<32768, 256, 0, stream>>>(x, xb, (long)MROWS * DMODEL);
  k_cv<<<1024, 256, 0, stream>>>(w_qkv, wvb);
  k_transpose<<<dim3(64, 32), dim3(32, 8), 0, stream>>>(w_qkv, wqkvT, DMODEL, QKVCOLS);
  k_transpose<<<dim3(32, 32), dim3(32, 8), 0, stream>>>(w_out, woutT, DMODEL, DMODEL);

  // qk GEMM (N=2048) with fused q-softmax / k-exp epilogue -> qhat/khat
  k_gemm256<0, DMODEL, DMODEL, 8, QKVCOLS, 0L>
      <<<dim3((MROWS / 256) * (2048 / 256)), 512, 0, stream>>>(
      xb, wqkvT, nullptr, qhat, khat, nullptr, S);

  k_ctx<<<dim3(64, 8), 256, 0, stream>>>(qhat, khat, cpart);
  k_ct<<<dim3(4, 16), 256, 0, stream>>>(woutT, cpart, S, ctT);
  // WcT[b] = CtT[b] @ Wv^T  (M=4096 stacked, N=1024, K=1024)
  k_wc<<<dim3(32, 8), 256, 0, stream>>>(ctT, wvb, wcT);

  // out GEMM: out = xb x WcT[b]^T + bias, fp32 store
  k_gemm256<1, DMODEL, DMODEL, 4, DMODEL, (long)DMODEL * DMODEL>
      <<<dim3((MROWS / 256) * (DMODEL / 256)), 512, 0, stream>>>(
      xb, wcT, b_out, nullptr, nullptr, out, nullptr);
}